// Round 1
// baseline (830.459 us; speedup 1.0000x reference)
//
#include <hip/hip_runtime.h>

#define NN 100000
#define NE 1600000

static __device__ __forceinline__ float lrelu(float x, float s) {
    return x > 0.f ? x : s * x;
}

// ---------------- CSR build ----------------

__global__ void hist_kernel(const int* __restrict__ dst, int* __restrict__ deg, int e) {
    int i = blockIdx.x * 256 + threadIdx.x;
    if (i < e) atomicAdd(&deg[dst[i]], 1);
}

// each block scans 1024 elements (256 threads x 4), writes exclusive partial + block sum
__global__ void scan1_kernel(const int* __restrict__ deg, int* __restrict__ part,
                             int* __restrict__ bsums, int n) {
    __shared__ int sd[256];
    int t = threadIdx.x;
    int base = blockIdx.x * 1024 + t * 4;
    int a0 = (base + 0 < n) ? deg[base + 0] : 0;
    int a1 = (base + 1 < n) ? deg[base + 1] : 0;
    int a2 = (base + 2 < n) ? deg[base + 2] : 0;
    int a3 = (base + 3 < n) ? deg[base + 3] : 0;
    int tsum = a0 + a1 + a2 + a3;
    sd[t] = tsum;
    __syncthreads();
    for (int off = 1; off < 256; off <<= 1) {
        int x = (t >= off) ? sd[t - off] : 0;
        __syncthreads();
        sd[t] += x;
        __syncthreads();
    }
    int excl = sd[t] - tsum;
    if (base + 0 < n) part[base + 0] = excl;
    if (base + 1 < n) part[base + 1] = excl + a0;
    if (base + 2 < n) part[base + 2] = excl + a0 + a1;
    if (base + 3 < n) part[base + 3] = excl + a0 + a1 + a2;
    if (t == 255) bsums[blockIdx.x] = sd[255];
}

__global__ void scan2_kernel(int* bsums, int nb) {
    __shared__ int sd[128];
    int t = threadIdx.x;
    int v = (t < nb) ? bsums[t] : 0;
    sd[t] = v;
    __syncthreads();
    for (int off = 1; off < 128; off <<= 1) {
        int x = (t >= off) ? sd[t - off] : 0;
        __syncthreads();
        sd[t] += x;
        __syncthreads();
    }
    if (t < nb) bsums[t] = sd[t] - v;  // exclusive
}

// offs[i] = part[i] + bsums[i/1024]; cursor[i] = same (fill start positions)
__global__ void scan3_kernel(const int* __restrict__ part, const int* __restrict__ bsums,
                             int* __restrict__ offs, int* __restrict__ cursor, int n) {
    int i = blockIdx.x * 256 + threadIdx.x;
    if (i < n) {
        int o = part[i] + bsums[i >> 10];
        offs[i] = o;
        cursor[i] = o;
    }
}

__global__ void fill_kernel(const int* __restrict__ srcs, const int* __restrict__ dsts,
                            int* cursor, int* __restrict__ csr, int e) {
    int i = blockIdx.x * 256 + threadIdx.x;
    if (i < e) {
        int d = dsts[i];
        int pos = atomicAdd(&cursor[d], 1);
        csr[pos] = srcs[i];
    }
}

// ---------------- f32 GEMM: C[n,ldc] = A[n,128] @ W[128,ldw] (64-col tile per block) ------

__global__ __launch_bounds__(256) void gemm_tile(const float* __restrict__ A,
                                                 const float* __restrict__ W,
                                                 float* __restrict__ C,
                                                 int n, int ldw, int ldc) {
    __shared__ float Wl[128][64];
    const int tid = threadIdx.x;
    const int j0 = blockIdx.y * 64;
    // stage W[:, j0:j0+64]
    for (int idx = tid; idx < 128 * 16; idx += 256) {
        int k = idx >> 4, j4 = (idx & 15) << 2;
        *(float4*)&Wl[k][j4] = *(const float4*)&W[k * ldw + j0 + j4];
    }
    __syncthreads();
    const int tx = tid & 15, ty = tid >> 4;
    const int row0 = blockIdx.x * 64 + ty * 4;
    float acc[4][4] = {};
    const float* Ab[4];
    bool ok[4];
#pragma unroll
    for (int r = 0; r < 4; r++) {
        int row = row0 + r;
        ok[r] = row < n;
        Ab[r] = A + (size_t)min(row, n - 1) * 128;
    }
    for (int k0 = 0; k0 < 128; k0 += 4) {
        float4 a[4];
#pragma unroll
        for (int r = 0; r < 4; r++) a[r] = *(const float4*)&Ab[r][k0];
#pragma unroll
        for (int kk = 0; kk < 4; kk++) {
            float4 b = *(const float4*)&Wl[k0 + kk][tx * 4];
#pragma unroll
            for (int r = 0; r < 4; r++) {
                float av = (&a[r].x)[kk];
                acc[r][0] += av * b.x;
                acc[r][1] += av * b.y;
                acc[r][2] += av * b.z;
                acc[r][3] += av * b.w;
            }
        }
    }
#pragma unroll
    for (int r = 0; r < 4; r++) {
        int row = row0 + r;
        if (ok[r])
            *(float4*)&C[(size_t)row * ldc + j0 + tx * 4] =
                make_float4(acc[r][0], acc[r][1], acc[r][2], acc[r][3]);
    }
}

// ---------------- attention coefficients ----------------

template <int H, int C>
__global__ void al_kernel(const float* __restrict__ h, const float* __restrict__ asrc,
                          const float* __restrict__ adst, float* __restrict__ als,
                          float* __restrict__ ald, int n) {
    int g = blockIdx.x * 256 + threadIdx.x;
    if (g >= n * H) return;
    int head = g % H;
    const float* hp = h + (size_t)(g / H) * (H * C) + head * C;
    const float* sp = asrc + head * C;
    const float* dp = adst + head * C;
    float s = 0.f, d = 0.f;
#pragma unroll
    for (int j = 0; j < C; j += 4) {
        float4 hv = *(const float4*)&hp[j];
        float4 sv = *(const float4*)&sp[j];
        float4 dv = *(const float4*)&dp[j];
        s += hv.x * sv.x + hv.y * sv.y + hv.z * sv.z + hv.w * sv.w;
        d += hv.x * dv.x + hv.y * dv.y + hv.z * dv.z + hv.w * dv.w;
    }
    als[g] = s;
    ald[g] = d;
}

// ---------------- GAT aggregation, 4 heads x 32 (F=128), wave per dst node ----------------

__global__ __launch_bounds__(256) void agg4_kernel(
    const float* __restrict__ h, const float* __restrict__ als, const float* __restrict__ ald,
    const int* __restrict__ offs, const int* __restrict__ cur, const int* __restrict__ csr,
    const float* __restrict__ bias, float* __restrict__ out, int n, int do_l1) {
    int v = blockIdx.x * 4 + (threadIdx.x >> 6);
    if (v >= n) return;
    int lane = threadIdx.x & 63;
    int hA = lane >> 5;  // 0/1 ; hB = hA+2
    float4 av = *(const float4*)&ald[v * 4];
    float4 sv = *(const float4*)&als[v * 4];
    float aldA = hA ? av.y : av.x;
    float aldB = hA ? av.w : av.z;
    int begin = offs[v], end = cur[v];

    // pass 1: per-head max over incoming edges (incl. self-loop)
    float m0 = lrelu(sv.x + av.x, 0.2f);
    float m1 = lrelu(sv.y + av.y, 0.2f);
    float m2 = lrelu(sv.z + av.z, 0.2f);
    float m3 = lrelu(sv.w + av.w, 0.2f);
    for (int i = begin + lane; i < end; i += 64) {
        int s = csr[i];
        float4 q = *(const float4*)&als[s * 4];
        m0 = fmaxf(m0, lrelu(q.x + av.x, 0.2f));
        m1 = fmaxf(m1, lrelu(q.y + av.y, 0.2f));
        m2 = fmaxf(m2, lrelu(q.z + av.z, 0.2f));
        m3 = fmaxf(m3, lrelu(q.w + av.w, 0.2f));
    }
#pragma unroll
    for (int o = 32; o > 0; o >>= 1) {
        m0 = fmaxf(m0, __shfl_xor(m0, o));
        m1 = fmaxf(m1, __shfl_xor(m1, o));
        m2 = fmaxf(m2, __shfl_xor(m2, o));
        m3 = fmaxf(m3, __shfl_xor(m3, o));
    }
    float mA = hA ? m1 : m0;
    float mB = hA ? m3 : m2;

    // pass 2: softmax-weighted accumulation
    float sA, sB, acc0, acc1;
    {
        float eA = lrelu((hA ? sv.y : sv.x) + aldA, 0.2f);
        float eB = lrelu((hA ? sv.w : sv.z) + aldB, 0.2f);
        float pA = __expf(eA - mA), pB = __expf(eB - mB);
        sA = pA;
        sB = pB;
        acc0 = pA * h[(size_t)v * 128 + lane];
        acc1 = pB * h[(size_t)v * 128 + 64 + lane];
    }
    for (int base = begin; base < end; base += 64) {
        int idx = base + lane;
        int myid = (idx < end) ? csr[idx] : 0;
        int cnt = min(64, end - base);
        for (int t = 0; t < cnt; ++t) {
            int s = __shfl(myid, t);
            float4 q = *(const float4*)&als[s * 4];
            float pA = __expf(lrelu((hA ? q.y : q.x) + aldA, 0.2f) - mA);
            float pB = __expf(lrelu((hA ? q.w : q.z) + aldB, 0.2f) - mB);
            sA += pA;
            sB += pB;
            const float* hp = h + (size_t)s * 128;
            acc0 += pA * hp[lane];
            acc1 += pB * hp[64 + lane];
        }
    }
    float o0 = acc0 / (sA + 1e-16f) + bias[lane];
    float o1 = acc1 / (sB + 1e-16f) + bias[64 + lane];
    o0 = lrelu(o0, 0.01f);
    o1 = lrelu(o1, 0.01f);
    if (do_l1) {
        float t = fabsf(o0) + fabsf(o1);
#pragma unroll
        for (int o = 32; o > 0; o >>= 1) t += __shfl_xor(t, o);
        float inv = 1.f / fmaxf(t, 1e-12f);
        o0 *= inv;
        o1 *= inv;
    }
    out[(size_t)v * 128 + lane] = o0;
    out[(size_t)v * 128 + 64 + lane] = o1;
}

// ---------------- GAT aggregation, 1 head x 64 (layer 2) + l1norm + relu -> d_out ---------

__global__ __launch_bounds__(256) void agg1_kernel(
    const float* __restrict__ h, const float* __restrict__ als, const float* __restrict__ ald,
    const int* __restrict__ offs, const int* __restrict__ cur, const int* __restrict__ csr,
    const float* __restrict__ bias, float* __restrict__ out, int n) {
    int v = blockIdx.x * 4 + (threadIdx.x >> 6);
    if (v >= n) return;
    int lane = threadIdx.x & 63;
    float aldv = ald[v];
    float alsv = als[v];
    int begin = offs[v], end = cur[v];

    float m = lrelu(alsv + aldv, 0.2f);
    for (int i = begin + lane; i < end; i += 64) {
        m = fmaxf(m, lrelu(als[csr[i]] + aldv, 0.2f));
    }
#pragma unroll
    for (int o = 32; o > 0; o >>= 1) m = fmaxf(m, __shfl_xor(m, o));

    float ssum, acc;
    {
        float p = __expf(lrelu(alsv + aldv, 0.2f) - m);
        ssum = p;
        acc = p * h[(size_t)v * 64 + lane];
    }
    for (int base = begin; base < end; base += 64) {
        int idx = base + lane;
        int myid = (idx < end) ? csr[idx] : 0;
        int cnt = min(64, end - base);
        for (int t = 0; t < cnt; ++t) {
            int s = __shfl(myid, t);
            float p = __expf(lrelu(als[s] + aldv, 0.2f) - m);
            ssum += p;
            acc += p * h[(size_t)s * 64 + lane];
        }
    }
    float o = acc / (ssum + 1e-16f) + bias[lane];
    float t = fabsf(o);
#pragma unroll
    for (int off = 32; off > 0; off >>= 1) t += __shfl_xor(t, off);
    o = o / fmaxf(t, 1e-12f);
    out[(size_t)v * 64 + lane] = fmaxf(o, 0.f);
}

// ---------------- launch ----------------

extern "C" void kernel_launch(void* const* d_in, const int* in_sizes, int n_in,
                              void* d_out, int out_size, void* d_ws, size_t ws_size,
                              hipStream_t stream) {
    const float* x = (const float*)d_in[0];
    const int* ei = (const int*)d_in[1];
    const float* W0 = (const float*)d_in[2];
    const float* b0 = (const float*)d_in[3];
    const float* as0 = (const float*)d_in[4];
    const float* ad0 = (const float*)d_in[5];
    const float* W1 = (const float*)d_in[6];
    const float* b1 = (const float*)d_in[7];
    const float* as1 = (const float*)d_in[8];
    const float* ad1 = (const float*)d_in[9];
    const float* W2 = (const float*)d_in[10];
    const float* b2 = (const float*)d_in[11];
    const float* as2 = (const float*)d_in[12];
    const float* ad2 = (const float*)d_in[13];
    float* outp = (float*)d_out;

    char* ws = (char*)d_ws;
    size_t off = 0;
    auto alloc = [&](size_t bytes) -> void* {
        void* p = ws + off;
        off = (off + bytes + 255) & ~(size_t)255;
        return p;
    };
    int* deg = (int*)alloc(NN * 4);
    int* offs = (int*)alloc(NN * 4);
    int* cursor = (int*)alloc(NN * 4);
    int* bsums = (int*)alloc(1024);
    int* csr = (int*)alloc((size_t)NE * 4);
    float* hbuf = (float*)alloc((size_t)NN * 128 * 4);
    float* nodeA = (float*)alloc((size_t)NN * 128 * 4);
    float* als = (float*)alloc(NN * 4 * 4);
    float* ald = (float*)alloc(NN * 4 * 4);

    const int* srcs = ei;
    const int* dsts = ei + NE;

    // CSR by destination (shared by all 3 layers; self-loops handled implicitly)
    hipMemsetAsync(deg, 0, NN * 4, stream);
    hist_kernel<<<(NE + 255) / 256, 256, 0, stream>>>(dsts, deg, NE);
    int nb = (NN + 1023) / 1024;  // 98
    scan1_kernel<<<nb, 256, 0, stream>>>(deg, offs, bsums, NN);
    scan2_kernel<<<1, 128, 0, stream>>>(bsums, nb);
    scan3_kernel<<<(NN + 255) / 256, 256, 0, stream>>>(offs, bsums, offs, cursor, NN);
    fill_kernel<<<(NE + 255) / 256, 256, 0, stream>>>(srcs, dsts, cursor, csr, NE);

    dim3 ggrid((NN + 63) / 64, 2);
    dim3 ggrid2((NN + 63) / 64, 1);
    int algrid = (NN * 4 + 255) / 256;
    int aggrid = (NN + 3) / 4;

    // layer 0
    gemm_tile<<<ggrid, 256, 0, stream>>>(x, W0, hbuf, NN, 128, 128);
    al_kernel<4, 32><<<algrid, 256, 0, stream>>>(hbuf, as0, ad0, als, ald, NN);
    agg4_kernel<<<aggrid, 256, 0, stream>>>(hbuf, als, ald, offs, cursor, csr, b0, nodeA, NN, 1);
    // layer 1
    gemm_tile<<<ggrid, 256, 0, stream>>>(nodeA, W1, hbuf, NN, 128, 128);
    al_kernel<4, 32><<<algrid, 256, 0, stream>>>(hbuf, as1, ad1, als, ald, NN);
    agg4_kernel<<<aggrid, 256, 0, stream>>>(hbuf, als, ald, offs, cursor, csr, b1, nodeA, NN, 0);
    // layer 2
    gemm_tile<<<ggrid2, 256, 0, stream>>>(nodeA, W2, hbuf, NN, 64, 64);
    al_kernel<1, 64><<<(NN + 255) / 256, 256, 0, stream>>>(hbuf, as2, ad2, als, ald, NN);
    agg1_kernel<<<aggrid, 256, 0, stream>>>(hbuf, als, ald, offs, cursor, csr, b2, outp, NN);
}

// Round 2
// 752.533 us; speedup vs baseline: 1.1036x; 1.1036x over previous
//
#include <hip/hip_runtime.h>

#define NN 100000
#define NE 1600000

static __device__ __forceinline__ float lrelu(float x, float s) {
    return x > 0.f ? x : s * x;
}

// ---------------- CSR build ----------------

__global__ void hist_kernel(const int* __restrict__ dst, int* __restrict__ deg, int e) {
    int i = blockIdx.x * 256 + threadIdx.x;
    if (i < e) atomicAdd(&deg[dst[i]], 1);
}

// each block scans 1024 elements (256 threads x 4), writes exclusive partial + block sum
__global__ void scan1_kernel(const int* __restrict__ deg, int* __restrict__ part,
                             int* __restrict__ bsums, int n) {
    __shared__ int sd[256];
    int t = threadIdx.x;
    int base = blockIdx.x * 1024 + t * 4;
    int a0 = (base + 0 < n) ? deg[base + 0] : 0;
    int a1 = (base + 1 < n) ? deg[base + 1] : 0;
    int a2 = (base + 2 < n) ? deg[base + 2] : 0;
    int a3 = (base + 3 < n) ? deg[base + 3] : 0;
    int tsum = a0 + a1 + a2 + a3;
    sd[t] = tsum;
    __syncthreads();
    for (int off = 1; off < 256; off <<= 1) {
        int x = (t >= off) ? sd[t - off] : 0;
        __syncthreads();
        sd[t] += x;
        __syncthreads();
    }
    int excl = sd[t] - tsum;
    if (base + 0 < n) part[base + 0] = excl;
    if (base + 1 < n) part[base + 1] = excl + a0;
    if (base + 2 < n) part[base + 2] = excl + a0 + a1;
    if (base + 3 < n) part[base + 3] = excl + a0 + a1 + a2;
    if (t == 255) bsums[blockIdx.x] = sd[255];
}

__global__ void scan2_kernel(int* bsums, int nb) {
    __shared__ int sd[128];
    int t = threadIdx.x;
    int v = (t < nb) ? bsums[t] : 0;
    sd[t] = v;
    __syncthreads();
    for (int off = 1; off < 128; off <<= 1) {
        int x = (t >= off) ? sd[t - off] : 0;
        __syncthreads();
        sd[t] += x;
        __syncthreads();
    }
    if (t < nb) bsums[t] = sd[t] - v;  // exclusive
}

__global__ void scan3_kernel(const int* __restrict__ part, const int* __restrict__ bsums,
                             int* __restrict__ offs, int* __restrict__ cursor, int n) {
    int i = blockIdx.x * 256 + threadIdx.x;
    if (i < n) {
        int o = part[i] + bsums[i >> 10];
        offs[i] = o;
        cursor[i] = o;
    }
}

__global__ void fill_kernel(const int* __restrict__ srcs, const int* __restrict__ dsts,
                            int* cursor, int* __restrict__ csr, int e) {
    int i = blockIdx.x * 256 + threadIdx.x;
    if (i < e) {
        int d = dsts[i];
        int pos = atomicAdd(&cursor[d], 1);
        csr[pos] = srcs[i];
    }
}

// ---------------- f32 GEMM: C[n,ldc] = A[n,128] @ W[128,ldw] (64-col tile per block) ------

__global__ __launch_bounds__(256) void gemm_tile(const float* __restrict__ A,
                                                 const float* __restrict__ W,
                                                 float* __restrict__ C,
                                                 int n, int ldw, int ldc) {
    __shared__ float Wl[128][64];
    const int tid = threadIdx.x;
    const int j0 = blockIdx.y * 64;
    for (int idx = tid; idx < 128 * 16; idx += 256) {
        int k = idx >> 4, j4 = (idx & 15) << 2;
        *(float4*)&Wl[k][j4] = *(const float4*)&W[k * ldw + j0 + j4];
    }
    __syncthreads();
    const int tx = tid & 15, ty = tid >> 4;
    const int row0 = blockIdx.x * 64 + ty * 4;
    float acc[4][4] = {};
    const float* Ab[4];
    bool ok[4];
#pragma unroll
    for (int r = 0; r < 4; r++) {
        int row = row0 + r;
        ok[r] = row < n;
        Ab[r] = A + (size_t)min(row, n - 1) * 128;
    }
    for (int k0 = 0; k0 < 128; k0 += 4) {
        float4 a[4];
#pragma unroll
        for (int r = 0; r < 4; r++) a[r] = *(const float4*)&Ab[r][k0];
#pragma unroll
        for (int kk = 0; kk < 4; kk++) {
            float4 b = *(const float4*)&Wl[k0 + kk][tx * 4];
#pragma unroll
            for (int r = 0; r < 4; r++) {
                float av = (&a[r].x)[kk];
                acc[r][0] += av * b.x;
                acc[r][1] += av * b.y;
                acc[r][2] += av * b.z;
                acc[r][3] += av * b.w;
            }
        }
    }
#pragma unroll
    for (int r = 0; r < 4; r++) {
        int row = row0 + r;
        if (ok[r])
            *(float4*)&C[(size_t)row * ldc + j0 + tx * 4] =
                make_float4(acc[r][0], acc[r][1], acc[r][2], acc[r][3]);
    }
}

// ---------------- attention coefficients ----------------

template <int H, int C>
__global__ void al_kernel(const float* __restrict__ h, const float* __restrict__ asrc,
                          const float* __restrict__ adst, float* __restrict__ als,
                          float* __restrict__ ald, int n) {
    int g = blockIdx.x * 256 + threadIdx.x;
    if (g >= n * H) return;
    int head = g % H;
    const float* hp = h + (size_t)(g / H) * (H * C) + head * C;
    const float* sp = asrc + head * C;
    const float* dp = adst + head * C;
    float s = 0.f, d = 0.f;
#pragma unroll
    for (int j = 0; j < C; j += 4) {
        float4 hv = *(const float4*)&hp[j];
        float4 sv = *(const float4*)&sp[j];
        float4 dv = *(const float4*)&dp[j];
        s += hv.x * sv.x + hv.y * sv.y + hv.z * sv.z + hv.w * sv.w;
        d += hv.x * dv.x + hv.y * dv.y + hv.z * dv.z + hv.w * dv.w;
    }
    als[g] = s;
    ald[g] = d;
}

// ---------------- GAT aggregation, 4 heads x 32 (F=128), wave per dst node ----------------
// Weights precomputed lane-parallel into LDS (no max-subtraction: logits are bounded,
// softmax is shift-invariant). Serial gather loop: LDS broadcast + float2 load + 2 FMA.
// Lane owns features (2*lane, 2*lane+1); head = lane>>4.

__global__ __launch_bounds__(256) void agg4_kernel(
    const float* __restrict__ h, const float* __restrict__ als, const float* __restrict__ ald,
    const int* __restrict__ offs, const int* __restrict__ cur, const int* __restrict__ csr,
    const float* __restrict__ bias, float* __restrict__ out, int n, int do_l1) {
    __shared__ int sid[4][64];
    __shared__ float sp[4][64][4];
    int w = threadIdx.x >> 6;
    int v = blockIdx.x * 4 + w;
    if (v >= n) return;
    int lane = threadIdx.x & 63;
    int hd = lane >> 4;  // head owning features 2*lane, 2*lane+1

    float4 av = *(const float4*)&ald[v * 4];
    float4 svv = *(const float4*)&als[v * 4];
    int begin = offs[v], end = cur[v];

    // self-loop weight (per head)
    float ps0 = __expf(lrelu(svv.x + av.x, 0.2f));
    float ps1 = __expf(lrelu(svv.y + av.y, 0.2f));
    float ps2 = __expf(lrelu(svv.z + av.z, 0.2f));
    float ps3 = __expf(lrelu(svv.w + av.w, 0.2f));
    float psel = hd == 0 ? ps0 : hd == 1 ? ps1 : hd == 2 ? ps2 : ps3;
    float2 hv = *(const float2*)&h[(size_t)v * 128 + 2 * lane];
    float acc0 = psel * hv.x, acc1 = psel * hv.y;
    float s0 = 0.f, s1 = 0.f, s2 = 0.f, s3 = 0.f;

    for (int base = begin; base < end; base += 64) {
        int idx = base + lane;
        int cnt = min(64, end - base);
        if (idx < end) {
            int s = csr[idx];
            float4 q = *(const float4*)&als[s * 4];
            float p0 = __expf(lrelu(q.x + av.x, 0.2f));
            float p1 = __expf(lrelu(q.y + av.y, 0.2f));
            float p2 = __expf(lrelu(q.z + av.z, 0.2f));
            float p3 = __expf(lrelu(q.w + av.w, 0.2f));
            sid[w][lane] = s;
            sp[w][lane][0] = p0;
            sp[w][lane][1] = p1;
            sp[w][lane][2] = p2;
            sp[w][lane][3] = p3;
            s0 += p0; s1 += p1; s2 += p2; s3 += p3;
        }
        asm volatile("s_waitcnt lgkmcnt(0)" ::: "memory");
        int t = 0;
        for (; t + 2 <= cnt; t += 2) {
            int sa = sid[w][t], sb = sid[w][t + 1];
            float pa = sp[w][t][hd], pb = sp[w][t + 1][hd];
            float2 ha = *(const float2*)&h[(size_t)sa * 128 + 2 * lane];
            float2 hb = *(const float2*)&h[(size_t)sb * 128 + 2 * lane];
            acc0 += pa * ha.x;
            acc1 += pa * ha.y;
            acc0 += pb * hb.x;
            acc1 += pb * hb.y;
        }
        if (t < cnt) {
            int sa = sid[w][t];
            float pa = sp[w][t][hd];
            float2 ha = *(const float2*)&h[(size_t)sa * 128 + 2 * lane];
            acc0 += pa * ha.x;
            acc1 += pa * ha.y;
        }
    }
#pragma unroll
    for (int o = 32; o > 0; o >>= 1) {
        s0 += __shfl_xor(s0, o);
        s1 += __shfl_xor(s1, o);
        s2 += __shfl_xor(s2, o);
        s3 += __shfl_xor(s3, o);
    }
    s0 += ps0; s1 += ps1; s2 += ps2; s3 += ps3;
    float ssel = hd == 0 ? s0 : hd == 1 ? s1 : hd == 2 ? s2 : s3;
    float inv = 1.f / (ssel + 1e-16f);
    float2 bv = *(const float2*)&bias[2 * lane];
    float o0 = lrelu(acc0 * inv + bv.x, 0.01f);
    float o1 = lrelu(acc1 * inv + bv.y, 0.01f);
    if (do_l1) {
        float t = fabsf(o0) + fabsf(o1);
#pragma unroll
        for (int o = 32; o > 0; o >>= 1) t += __shfl_xor(t, o);
        float li = 1.f / fmaxf(t, 1e-12f);
        o0 *= li;
        o1 *= li;
    }
    *(float2*)&out[(size_t)v * 128 + 2 * lane] = make_float2(o0, o1);
}

// ---------------- GAT aggregation, 1 head x 64 (layer 2) + l1norm + relu -> d_out ---------

__global__ __launch_bounds__(256) void agg1_kernel(
    const float* __restrict__ h, const float* __restrict__ als, const float* __restrict__ ald,
    const int* __restrict__ offs, const int* __restrict__ cur, const int* __restrict__ csr,
    const float* __restrict__ bias, float* __restrict__ out, int n) {
    __shared__ int sid[4][64];
    __shared__ float sp[4][64];
    int w = threadIdx.x >> 6;
    int v = blockIdx.x * 4 + w;
    if (v >= n) return;
    int lane = threadIdx.x & 63;
    float aldv = ald[v];
    float alsv = als[v];
    int begin = offs[v], end = cur[v];

    float pself = __expf(lrelu(alsv + aldv, 0.2f));
    float acc = pself * h[(size_t)v * 64 + lane];
    float ssum = 0.f;

    for (int base = begin; base < end; base += 64) {
        int idx = base + lane;
        int cnt = min(64, end - base);
        if (idx < end) {
            int s = csr[idx];
            float p = __expf(lrelu(als[s] + aldv, 0.2f));
            sid[w][lane] = s;
            sp[w][lane] = p;
            ssum += p;
        }
        asm volatile("s_waitcnt lgkmcnt(0)" ::: "memory");
        int t = 0;
        for (; t + 2 <= cnt; t += 2) {
            int sa = sid[w][t], sb = sid[w][t + 1];
            float pa = sp[w][t], pb = sp[w][t + 1];
            float ha = h[(size_t)sa * 64 + lane];
            float hb = h[(size_t)sb * 64 + lane];
            acc += pa * ha;
            acc += pb * hb;
        }
        if (t < cnt) {
            int sa = sid[w][t];
            float pa = sp[w][t];
            acc += pa * h[(size_t)sa * 64 + lane];
        }
    }
#pragma unroll
    for (int o = 32; o > 0; o >>= 1) ssum += __shfl_xor(ssum, o);
    ssum += pself;
    float o = acc / (ssum + 1e-16f) + bias[lane];
    float t = fabsf(o);
#pragma unroll
    for (int off = 32; off > 0; off >>= 1) t += __shfl_xor(t, off);
    o = o / fmaxf(t, 1e-12f);
    out[(size_t)v * 64 + lane] = fmaxf(o, 0.f);
}

// ---------------- launch ----------------

extern "C" void kernel_launch(void* const* d_in, const int* in_sizes, int n_in,
                              void* d_out, int out_size, void* d_ws, size_t ws_size,
                              hipStream_t stream) {
    const float* x = (const float*)d_in[0];
    const int* ei = (const int*)d_in[1];
    const float* W0 = (const float*)d_in[2];
    const float* b0 = (const float*)d_in[3];
    const float* as0 = (const float*)d_in[4];
    const float* ad0 = (const float*)d_in[5];
    const float* W1 = (const float*)d_in[6];
    const float* b1 = (const float*)d_in[7];
    const float* as1 = (const float*)d_in[8];
    const float* ad1 = (const float*)d_in[9];
    const float* W2 = (const float*)d_in[10];
    const float* b2 = (const float*)d_in[11];
    const float* as2 = (const float*)d_in[12];
    const float* ad2 = (const float*)d_in[13];
    float* outp = (float*)d_out;

    char* ws = (char*)d_ws;
    size_t off = 0;
    auto alloc = [&](size_t bytes) -> void* {
        void* p = ws + off;
        off = (off + bytes + 255) & ~(size_t)255;
        return p;
    };
    int* deg = (int*)alloc(NN * 4);
    int* offs = (int*)alloc(NN * 4);
    int* cursor = (int*)alloc(NN * 4);
    int* bsums = (int*)alloc(1024);
    int* csr = (int*)alloc((size_t)NE * 4);
    float* hbuf = (float*)alloc((size_t)NN * 128 * 4);
    float* nodeA = (float*)alloc((size_t)NN * 128 * 4);
    float* als = (float*)alloc(NN * 4 * 4);
    float* ald = (float*)alloc(NN * 4 * 4);

    const int* srcs = ei;
    const int* dsts = ei + NE;

    hipMemsetAsync(deg, 0, NN * 4, stream);
    hist_kernel<<<(NE + 255) / 256, 256, 0, stream>>>(dsts, deg, NE);
    int nb = (NN + 1023) / 1024;  // 98
    scan1_kernel<<<nb, 256, 0, stream>>>(deg, offs, bsums, NN);
    scan2_kernel<<<1, 128, 0, stream>>>(bsums, nb);
    scan3_kernel<<<(NN + 255) / 256, 256, 0, stream>>>(offs, bsums, offs, cursor, NN);
    fill_kernel<<<(NE + 255) / 256, 256, 0, stream>>>(srcs, dsts, cursor, csr, NE);

    dim3 ggrid((NN + 63) / 64, 2);
    dim3 ggrid2((NN + 63) / 64, 1);
    int algrid = (NN * 4 + 255) / 256;
    int aggrid = (NN + 3) / 4;

    // layer 0
    gemm_tile<<<ggrid, 256, 0, stream>>>(x, W0, hbuf, NN, 128, 128);
    al_kernel<4, 32><<<algrid, 256, 0, stream>>>(hbuf, as0, ad0, als, ald, NN);
    agg4_kernel<<<aggrid, 256, 0, stream>>>(hbuf, als, ald, offs, cursor, csr, b0, nodeA, NN, 1);
    // layer 1
    gemm_tile<<<ggrid, 256, 0, stream>>>(nodeA, W1, hbuf, NN, 128, 128);
    al_kernel<4, 32><<<algrid, 256, 0, stream>>>(hbuf, as1, ad1, als, ald, NN);
    agg4_kernel<<<aggrid, 256, 0, stream>>>(hbuf, als, ald, offs, cursor, csr, b1, nodeA, NN, 0);
    // layer 2
    gemm_tile<<<ggrid2, 256, 0, stream>>>(nodeA, W2, hbuf, NN, 64, 64);
    al_kernel<1, 64><<<(NN + 255) / 256, 256, 0, stream>>>(hbuf, as2, ad2, als, ald, NN);
    agg1_kernel<<<aggrid, 256, 0, stream>>>(hbuf, als, ald, offs, cursor, csr, b2, outp, NN);
}

// Round 3
// 623.694 us; speedup vs baseline: 1.3315x; 1.2066x over previous
//
#include <hip/hip_runtime.h>
#include <hip/hip_bf16.h>

#define NN 100000
#define NE 1600000

static __device__ __forceinline__ float lrelu(float x, float s) {
    return x > 0.f ? x : s * x;
}

struct alignas(8) b4 {
    __hip_bfloat16 v[4];
};

// ---------------- CSR build ----------------

__global__ void hist_kernel(const int* __restrict__ dst, int* __restrict__ deg, int e) {
    int i = blockIdx.x * 256 + threadIdx.x;
    if (i < e) atomicAdd(&deg[dst[i]], 1);
}

__global__ void scan1_kernel(const int* __restrict__ deg, int* __restrict__ part,
                             int* __restrict__ bsums, int n) {
    __shared__ int sd[256];
    int t = threadIdx.x;
    int base = blockIdx.x * 1024 + t * 4;
    int a0 = (base + 0 < n) ? deg[base + 0] : 0;
    int a1 = (base + 1 < n) ? deg[base + 1] : 0;
    int a2 = (base + 2 < n) ? deg[base + 2] : 0;
    int a3 = (base + 3 < n) ? deg[base + 3] : 0;
    int tsum = a0 + a1 + a2 + a3;
    sd[t] = tsum;
    __syncthreads();
    for (int off = 1; off < 256; off <<= 1) {
        int x = (t >= off) ? sd[t - off] : 0;
        __syncthreads();
        sd[t] += x;
        __syncthreads();
    }
    int excl = sd[t] - tsum;
    if (base + 0 < n) part[base + 0] = excl;
    if (base + 1 < n) part[base + 1] = excl + a0;
    if (base + 2 < n) part[base + 2] = excl + a0 + a1;
    if (base + 3 < n) part[base + 3] = excl + a0 + a1 + a2;
    if (t == 255) bsums[blockIdx.x] = sd[255];
}

__global__ void scan2_kernel(int* bsums, int nb) {
    __shared__ int sd[128];
    int t = threadIdx.x;
    int v = (t < nb) ? bsums[t] : 0;
    sd[t] = v;
    __syncthreads();
    for (int off = 1; off < 128; off <<= 1) {
        int x = (t >= off) ? sd[t - off] : 0;
        __syncthreads();
        sd[t] += x;
        __syncthreads();
    }
    if (t < nb) bsums[t] = sd[t] - v;  // exclusive
}

__global__ void scan3_kernel(const int* __restrict__ part, const int* __restrict__ bsums,
                             int* __restrict__ offs, int* __restrict__ cursor, int n) {
    int i = blockIdx.x * 256 + threadIdx.x;
    if (i < n) {
        int o = part[i] + bsums[i >> 10];
        offs[i] = o;
        cursor[i] = o;
    }
}

__global__ void fill_kernel(const int* __restrict__ srcs, const int* __restrict__ dsts,
                            int* cursor, int* __restrict__ csr, int e) {
    int i = blockIdx.x * 256 + threadIdx.x;
    if (i < e) {
        int d = dsts[i];
        int pos = atomicAdd(&cursor[d], 1);
        csr[pos] = srcs[i];
    }
}

// ---------------- f32 GEMM: C = A[n,128] @ W[128,ldw]; also writes bf16 copy ------

__global__ __launch_bounds__(256) void gemm_tile(const float* __restrict__ A,
                                                 const float* __restrict__ W,
                                                 float* __restrict__ C,
                                                 __hip_bfloat16* __restrict__ Cb,
                                                 int n, int ldw, int ldc) {
    __shared__ float Wl[128][64];
    const int tid = threadIdx.x;
    const int j0 = blockIdx.y * 64;
    for (int idx = tid; idx < 128 * 16; idx += 256) {
        int k = idx >> 4, j4 = (idx & 15) << 2;
        *(float4*)&Wl[k][j4] = *(const float4*)&W[k * ldw + j0 + j4];
    }
    __syncthreads();
    const int tx = tid & 15, ty = tid >> 4;
    const int row0 = blockIdx.x * 64 + ty * 4;
    float acc[4][4] = {};
    const float* Ab[4];
    bool ok[4];
#pragma unroll
    for (int r = 0; r < 4; r++) {
        int row = row0 + r;
        ok[r] = row < n;
        Ab[r] = A + (size_t)min(row, n - 1) * 128;
    }
    for (int k0 = 0; k0 < 128; k0 += 4) {
        float4 a[4];
#pragma unroll
        for (int r = 0; r < 4; r++) a[r] = *(const float4*)&Ab[r][k0];
#pragma unroll
        for (int kk = 0; kk < 4; kk++) {
            float4 b = *(const float4*)&Wl[k0 + kk][tx * 4];
#pragma unroll
            for (int r = 0; r < 4; r++) {
                float av = (&a[r].x)[kk];
                acc[r][0] += av * b.x;
                acc[r][1] += av * b.y;
                acc[r][2] += av * b.z;
                acc[r][3] += av * b.w;
            }
        }
    }
#pragma unroll
    for (int r = 0; r < 4; r++) {
        int row = row0 + r;
        if (ok[r]) {
            *(float4*)&C[(size_t)row * ldc + j0 + tx * 4] =
                make_float4(acc[r][0], acc[r][1], acc[r][2], acc[r][3]);
            b4 t;
            t.v[0] = __float2bfloat16(acc[r][0]);
            t.v[1] = __float2bfloat16(acc[r][1]);
            t.v[2] = __float2bfloat16(acc[r][2]);
            t.v[3] = __float2bfloat16(acc[r][3]);
            *(b4*)&Cb[(size_t)row * ldc + j0 + tx * 4] = t;
        }
    }
}

// ---------------- attention coefficients ----------------

template <int H, int C>
__global__ void al_kernel(const float* __restrict__ h, const float* __restrict__ asrc,
                          const float* __restrict__ adst, float* __restrict__ als,
                          float* __restrict__ ald, int n) {
    int g = blockIdx.x * 256 + threadIdx.x;
    if (g >= n * H) return;
    int head = g % H;
    const float* hp = h + (size_t)(g / H) * (H * C) + head * C;
    const float* sp = asrc + head * C;
    const float* dp = adst + head * C;
    float s = 0.f, d = 0.f;
#pragma unroll
    for (int j = 0; j < C; j += 4) {
        float4 hv = *(const float4*)&hp[j];
        float4 sv = *(const float4*)&sp[j];
        float4 dv = *(const float4*)&dp[j];
        s += hv.x * sv.x + hv.y * sv.y + hv.z * sv.z + hv.w * sv.w;
        d += hv.x * dv.x + hv.y * dv.y + hv.z * dv.z + hv.w * dv.w;
    }
    als[g] = s;
    ald[g] = d;
}

// ---------------- GAT aggregation, 4 heads (F=128), wave per dst node ----------------
// Gather from bf16 feature copy (half the bytes). LDS stores BYTE OFFSETS (s*256).
// Lane owns features (2*lane, 2*lane+1); head = lane>>4.

__global__ __launch_bounds__(256) void agg4_kernel(
    const char* __restrict__ hb, const float* __restrict__ als, const float* __restrict__ ald,
    const int* __restrict__ offs, const int* __restrict__ cur, const int* __restrict__ csr,
    const float* __restrict__ bias, float* __restrict__ out, int n, int do_l1) {
    __shared__ int soff[4][64];
    __shared__ float sp[4][64][4];
    int w = threadIdx.x >> 6;
    int v = blockIdx.x * 4 + w;
    if (v >= n) return;
    int lane = threadIdx.x & 63;
    int hd = lane >> 4;
    int lane4 = lane << 2;

    float4 av = *(const float4*)&ald[v * 4];
    float4 svv = *(const float4*)&als[v * 4];
    int begin = offs[v], end = cur[v];

    float ps0 = __expf(lrelu(svv.x + av.x, 0.2f));
    float ps1 = __expf(lrelu(svv.y + av.y, 0.2f));
    float ps2 = __expf(lrelu(svv.z + av.z, 0.2f));
    float ps3 = __expf(lrelu(svv.w + av.w, 0.2f));
    float psel = hd == 0 ? ps0 : hd == 1 ? ps1 : hd == 2 ? ps2 : ps3;
    unsigned uv = *(const unsigned*)(hb + (size_t)v * 256 + lane4);
    float acc0 = psel * __uint_as_float(uv << 16);
    float acc1 = psel * __uint_as_float(uv & 0xFFFF0000u);
    float s0 = 0.f, s1 = 0.f, s2 = 0.f, s3 = 0.f;

    for (int base = begin; base < end; base += 64) {
        int idx = base + lane;
        int cnt = min(64, end - base);
        if (idx < end) {
            int s = csr[idx];
            float4 q = *(const float4*)&als[s * 4];
            float p0 = __expf(lrelu(q.x + av.x, 0.2f));
            float p1 = __expf(lrelu(q.y + av.y, 0.2f));
            float p2 = __expf(lrelu(q.z + av.z, 0.2f));
            float p3 = __expf(lrelu(q.w + av.w, 0.2f));
            soff[w][lane] = s << 8;  // byte offset into bf16 rows (128*2B)
            sp[w][lane][0] = p0;
            sp[w][lane][1] = p1;
            sp[w][lane][2] = p2;
            sp[w][lane][3] = p3;
            s0 += p0; s1 += p1; s2 += p2; s3 += p3;
        }
        asm volatile("s_waitcnt lgkmcnt(0)" ::: "memory");
        int t = 0;
        for (; t + 4 <= cnt; t += 4) {
            int oa = soff[w][t + 0], ob = soff[w][t + 1];
            int oc = soff[w][t + 2], od = soff[w][t + 3];
            float pa = sp[w][t + 0][hd], pb = sp[w][t + 1][hd];
            float pc = sp[w][t + 2][hd], pd = sp[w][t + 3][hd];
            unsigned ua = *(const unsigned*)(hb + oa + lane4);
            unsigned ub = *(const unsigned*)(hb + ob + lane4);
            unsigned uc = *(const unsigned*)(hb + oc + lane4);
            unsigned ud = *(const unsigned*)(hb + od + lane4);
            acc0 += pa * __uint_as_float(ua << 16);
            acc1 += pa * __uint_as_float(ua & 0xFFFF0000u);
            acc0 += pb * __uint_as_float(ub << 16);
            acc1 += pb * __uint_as_float(ub & 0xFFFF0000u);
            acc0 += pc * __uint_as_float(uc << 16);
            acc1 += pc * __uint_as_float(uc & 0xFFFF0000u);
            acc0 += pd * __uint_as_float(ud << 16);
            acc1 += pd * __uint_as_float(ud & 0xFFFF0000u);
        }
        for (; t < cnt; ++t) {
            int oa = soff[w][t];
            float pa = sp[w][t][hd];
            unsigned ua = *(const unsigned*)(hb + oa + lane4);
            acc0 += pa * __uint_as_float(ua << 16);
            acc1 += pa * __uint_as_float(ua & 0xFFFF0000u);
        }
    }
#pragma unroll
    for (int o = 32; o > 0; o >>= 1) {
        s0 += __shfl_xor(s0, o);
        s1 += __shfl_xor(s1, o);
        s2 += __shfl_xor(s2, o);
        s3 += __shfl_xor(s3, o);
    }
    s0 += ps0; s1 += ps1; s2 += ps2; s3 += ps3;
    float ssel = hd == 0 ? s0 : hd == 1 ? s1 : hd == 2 ? s2 : s3;
    float inv = 1.f / (ssel + 1e-16f);
    float2 bv = *(const float2*)&bias[2 * lane];
    float o0 = lrelu(acc0 * inv + bv.x, 0.01f);
    float o1 = lrelu(acc1 * inv + bv.y, 0.01f);
    if (do_l1) {
        float t = fabsf(o0) + fabsf(o1);
#pragma unroll
        for (int o = 32; o > 0; o >>= 1) t += __shfl_xor(t, o);
        float li = 1.f / fmaxf(t, 1e-12f);
        o0 *= li;
        o1 *= li;
    }
    *(float2*)&out[(size_t)v * 128 + 2 * lane] = make_float2(o0, o1);
}

// ---------------- GAT aggregation, 1 head x 64 (layer 2) + l1norm + relu -> d_out ---------

__global__ __launch_bounds__(256) void agg1_kernel(
    const char* __restrict__ hb, const float* __restrict__ als, const float* __restrict__ ald,
    const int* __restrict__ offs, const int* __restrict__ cur, const int* __restrict__ csr,
    const float* __restrict__ bias, float* __restrict__ out, int n) {
    __shared__ int soff[4][64];
    __shared__ float sp[4][64];
    int w = threadIdx.x >> 6;
    int v = blockIdx.x * 4 + w;
    if (v >= n) return;
    int lane = threadIdx.x & 63;
    int lane2 = lane << 1;
    float aldv = ald[v];
    float alsv = als[v];
    int begin = offs[v], end = cur[v];

    float pself = __expf(lrelu(alsv + aldv, 0.2f));
    unsigned short usv = *(const unsigned short*)(hb + (size_t)v * 128 + lane2);
    float acc = pself * __uint_as_float(((unsigned)usv) << 16);
    float ssum = 0.f;

    for (int base = begin; base < end; base += 64) {
        int idx = base + lane;
        int cnt = min(64, end - base);
        if (idx < end) {
            int s = csr[idx];
            float p = __expf(lrelu(als[s] + aldv, 0.2f));
            soff[w][lane] = s << 7;  // byte offset into bf16 rows (64*2B)
            sp[w][lane] = p;
            ssum += p;
        }
        asm volatile("s_waitcnt lgkmcnt(0)" ::: "memory");
        int t = 0;
        for (; t + 4 <= cnt; t += 4) {
            int oa = soff[w][t + 0], ob = soff[w][t + 1];
            int oc = soff[w][t + 2], od = soff[w][t + 3];
            float pa = sp[w][t + 0], pb = sp[w][t + 1];
            float pc = sp[w][t + 2], pd = sp[w][t + 3];
            unsigned short ua = *(const unsigned short*)(hb + oa + lane2);
            unsigned short ub = *(const unsigned short*)(hb + ob + lane2);
            unsigned short uc = *(const unsigned short*)(hb + oc + lane2);
            unsigned short ud = *(const unsigned short*)(hb + od + lane2);
            acc += pa * __uint_as_float(((unsigned)ua) << 16);
            acc += pb * __uint_as_float(((unsigned)ub) << 16);
            acc += pc * __uint_as_float(((unsigned)uc) << 16);
            acc += pd * __uint_as_float(((unsigned)ud) << 16);
        }
        for (; t < cnt; ++t) {
            int oa = soff[w][t];
            float pa = sp[w][t];
            unsigned short ua = *(const unsigned short*)(hb + oa + lane2);
            acc += pa * __uint_as_float(((unsigned)ua) << 16);
        }
    }
#pragma unroll
    for (int o = 32; o > 0; o >>= 1) ssum += __shfl_xor(ssum, o);
    ssum += pself;
    float o = acc / (ssum + 1e-16f) + bias[lane];
    float t = fabsf(o);
#pragma unroll
    for (int off = 32; off > 0; off >>= 1) t += __shfl_xor(t, off);
    o = o / fmaxf(t, 1e-12f);
    out[(size_t)v * 64 + lane] = fmaxf(o, 0.f);
}

// ---------------- launch ----------------

extern "C" void kernel_launch(void* const* d_in, const int* in_sizes, int n_in,
                              void* d_out, int out_size, void* d_ws, size_t ws_size,
                              hipStream_t stream) {
    const float* x = (const float*)d_in[0];
    const int* ei = (const int*)d_in[1];
    const float* W0 = (const float*)d_in[2];
    const float* b0 = (const float*)d_in[3];
    const float* as0 = (const float*)d_in[4];
    const float* ad0 = (const float*)d_in[5];
    const float* W1 = (const float*)d_in[6];
    const float* b1 = (const float*)d_in[7];
    const float* as1 = (const float*)d_in[8];
    const float* ad1 = (const float*)d_in[9];
    const float* W2 = (const float*)d_in[10];
    const float* b2 = (const float*)d_in[11];
    const float* as2 = (const float*)d_in[12];
    const float* ad2 = (const float*)d_in[13];
    float* outp = (float*)d_out;

    char* ws = (char*)d_ws;
    size_t off = 0;
    auto alloc = [&](size_t bytes) -> void* {
        void* p = ws + off;
        off = (off + bytes + 255) & ~(size_t)255;
        return p;
    };
    int* deg = (int*)alloc(NN * 4);
    int* offs = (int*)alloc(NN * 4);
    int* cursor = (int*)alloc(NN * 4);
    int* bsums = (int*)alloc(1024);
    int* csr = (int*)alloc((size_t)NE * 4);
    float* hbuf = (float*)alloc((size_t)NN * 128 * 4);
    float* nodeA = (float*)alloc((size_t)NN * 128 * 4);
    __hip_bfloat16* h16 = (__hip_bfloat16*)alloc((size_t)NN * 128 * 2);
    float* als = (float*)alloc(NN * 4 * 4);
    float* ald = (float*)alloc(NN * 4 * 4);

    const int* srcs = ei;
    const int* dsts = ei + NE;

    hipMemsetAsync(deg, 0, NN * 4, stream);
    hist_kernel<<<(NE + 255) / 256, 256, 0, stream>>>(dsts, deg, NE);
    int nb = (NN + 1023) / 1024;  // 98
    scan1_kernel<<<nb, 256, 0, stream>>>(deg, offs, bsums, NN);
    scan2_kernel<<<1, 128, 0, stream>>>(bsums, nb);
    scan3_kernel<<<(NN + 255) / 256, 256, 0, stream>>>(offs, bsums, offs, cursor, NN);
    fill_kernel<<<(NE + 255) / 256, 256, 0, stream>>>(srcs, dsts, cursor, csr, NE);

    dim3 ggrid((NN + 63) / 64, 2);
    dim3 ggrid2((NN + 63) / 64, 1);
    int algrid = (NN * 4 + 255) / 256;
    int aggrid = (NN + 3) / 4;

    // layer 0
    gemm_tile<<<ggrid, 256, 0, stream>>>(x, W0, hbuf, h16, NN, 128, 128);
    al_kernel<4, 32><<<algrid, 256, 0, stream>>>(hbuf, as0, ad0, als, ald, NN);
    agg4_kernel<<<aggrid, 256, 0, stream>>>((const char*)h16, als, ald, offs, cursor, csr, b0,
                                            nodeA, NN, 1);
    // layer 1
    gemm_tile<<<ggrid, 256, 0, stream>>>(nodeA, W1, hbuf, h16, NN, 128, 128);
    al_kernel<4, 32><<<algrid, 256, 0, stream>>>(hbuf, as1, ad1, als, ald, NN);
    agg4_kernel<<<aggrid, 256, 0, stream>>>((const char*)h16, als, ald, offs, cursor, csr, b1,
                                            nodeA, NN, 0);
    // layer 2
    gemm_tile<<<ggrid2, 256, 0, stream>>>(nodeA, W2, hbuf, h16, NN, 64, 64);
    al_kernel<1, 64><<<(NN + 255) / 256, 256, 0, stream>>>(hbuf, as2, ad2, als, ald, NN);
    agg1_kernel<<<aggrid, 256, 0, stream>>>((const char*)h16, als, ald, offs, cursor, csr, b2,
                                            outp, NN);
}

// Round 4
// 499.094 us; speedup vs baseline: 1.6639x; 1.2497x over previous
//
#include <hip/hip_runtime.h>
#include <hip/hip_bf16.h>

#define NN 100000
#define NE 1600000
#define NB 391      // buckets of 256 nodes: (100000 + 255) >> 8
#define CHUNK 4096  // edges per partition block

static __device__ __forceinline__ float lrelu(float x, float s) {
    return x > 0.f ? x : s * x;
}

struct alignas(8) b4 {
    __hip_bfloat16 v[4];
};

// ---------------- CSR build: two-level counting sort ----------------

// grid-stride; LDS-aggregated bucket histogram
__global__ __launch_bounds__(256) void bucket_hist(const int* __restrict__ dsts,
                                                   int* __restrict__ bcnt) {
    __shared__ int hist[NB];
    for (int t = threadIdx.x; t < NB; t += 256) hist[t] = 0;
    __syncthreads();
    int stride = gridDim.x * 256;
    for (int e = blockIdx.x * 256 + threadIdx.x; e < NE; e += stride)
        atomicAdd(&hist[dsts[e] >> 8], 1);
    __syncthreads();
    for (int t = threadIdx.x; t < NB; t += 256) {
        int c = hist[t];
        if (c) atomicAdd(&bcnt[t], c);
    }
}

// single block: exclusive scan of bcnt -> bbase[NB+1], init bcursor
__global__ __launch_bounds__(512) void bucket_scan(const int* __restrict__ bcnt,
                                                   int* __restrict__ bbase,
                                                   int* __restrict__ bcursor) {
    __shared__ int sd[512];
    int t = threadIdx.x;
    int v = (t < NB) ? bcnt[t] : 0;
    sd[t] = v;
    __syncthreads();
    for (int off = 1; off < 512; off <<= 1) {
        int x = (t >= off) ? sd[t - off] : 0;
        __syncthreads();
        sd[t] += x;
        __syncthreads();
    }
    int excl = sd[t] - v;
    if (t < NB) {
        bbase[t] = excl;
        bcursor[t] = excl;
    }
    if (t == NB - 1) bbase[NB] = excl + v;
}

// partition edges into bucket regions as packed (src,dst)
__global__ __launch_bounds__(256) void partition_kernel(const int* __restrict__ srcs,
                                                        const int* __restrict__ dsts,
                                                        int* bcursor,
                                                        int2* __restrict__ part) {
    __shared__ int hist[NB];
    __shared__ int lbase[NB];
    for (int t = threadIdx.x; t < NB; t += 256) hist[t] = 0;
    __syncthreads();
    int e0 = blockIdx.x * CHUNK;
#pragma unroll
    for (int k = 0; k < CHUNK / 256; k++) {
        int e = e0 + k * 256 + threadIdx.x;
        if (e < NE) atomicAdd(&hist[dsts[e] >> 8], 1);
    }
    __syncthreads();
    for (int t = threadIdx.x; t < NB; t += 256) {
        int c = hist[t];
        if (c) lbase[t] = atomicAdd(&bcursor[t], c);
        hist[t] = 0;  // reuse as local cursor
    }
    __syncthreads();
#pragma unroll
    for (int k = 0; k < CHUNK / 256; k++) {
        int e = e0 + k * 256 + threadIdx.x;
        if (e < NE) {
            int s = srcs[e], d = dsts[e];
            int b = d >> 8;
            int r = atomicAdd(&hist[b], 1);
            part[lbase[b] + r] = make_int2(s, d);
        }
    }
}

// one block per bucket: per-node degree + scan in LDS -> offs, then place csr
__global__ __launch_bounds__(256) void bucket_fill(const int2* __restrict__ part,
                                                   const int* __restrict__ bbase,
                                                   int* __restrict__ offs,
                                                   int* __restrict__ csr) {
    __shared__ int lcur[256];
    __shared__ int sd[256];
    int b = blockIdx.x;
    int t = threadIdx.x;
    int ebeg = bbase[b], eend = bbase[b + 1];
    int node0 = b << 8;
    int nNodes = min(256, NN - node0);
    lcur[t] = 0;
    __syncthreads();
    for (int e = ebeg + t; e < eend; e += 256) {
        int2 p = part[e];
        atomicAdd(&lcur[p.y - node0], 1);
    }
    __syncthreads();
    int cnt = lcur[t];
    sd[t] = cnt;
    __syncthreads();
    for (int off = 1; off < 256; off <<= 1) {
        int x = (t >= off) ? sd[t - off] : 0;
        __syncthreads();
        sd[t] += x;
        __syncthreads();
    }
    int start = ebeg + sd[t] - cnt;
    if (t < nNodes) offs[node0 + t] = start;
    if (b == NB - 1 && t == 0) offs[NN] = NE;
    lcur[t] = start;
    __syncthreads();
    for (int e = ebeg + t; e < eend; e += 256) {
        int2 p = part[e];
        int pos = atomicAdd(&lcur[p.y - node0], 1);
        csr[pos] = p.x;
    }
}

// ---------------- f32 GEMM: C = A[n,128] @ W[128,ldw]; also writes bf16 copy ------

__global__ __launch_bounds__(256) void gemm_tile(const float* __restrict__ A,
                                                 const float* __restrict__ W,
                                                 float* __restrict__ C,
                                                 __hip_bfloat16* __restrict__ Cb,
                                                 int n, int ldw, int ldc) {
    __shared__ float Wl[128][64];
    const int tid = threadIdx.x;
    const int j0 = blockIdx.y * 64;
    for (int idx = tid; idx < 128 * 16; idx += 256) {
        int k = idx >> 4, j4 = (idx & 15) << 2;
        *(float4*)&Wl[k][j4] = *(const float4*)&W[k * ldw + j0 + j4];
    }
    __syncthreads();
    const int tx = tid & 15, ty = tid >> 4;
    const int row0 = blockIdx.x * 64 + ty * 4;
    float acc[4][4] = {};
    const float* Ab[4];
    bool ok[4];
#pragma unroll
    for (int r = 0; r < 4; r++) {
        int row = row0 + r;
        ok[r] = row < n;
        Ab[r] = A + (size_t)min(row, n - 1) * 128;
    }
    for (int k0 = 0; k0 < 128; k0 += 4) {
        float4 a[4];
#pragma unroll
        for (int r = 0; r < 4; r++) a[r] = *(const float4*)&Ab[r][k0];
#pragma unroll
        for (int kk = 0; kk < 4; kk++) {
            float4 b = *(const float4*)&Wl[k0 + kk][tx * 4];
#pragma unroll
            for (int r = 0; r < 4; r++) {
                float av = (&a[r].x)[kk];
                acc[r][0] += av * b.x;
                acc[r][1] += av * b.y;
                acc[r][2] += av * b.z;
                acc[r][3] += av * b.w;
            }
        }
    }
#pragma unroll
    for (int r = 0; r < 4; r++) {
        int row = row0 + r;
        if (ok[r]) {
            *(float4*)&C[(size_t)row * ldc + j0 + tx * 4] =
                make_float4(acc[r][0], acc[r][1], acc[r][2], acc[r][3]);
            b4 t;
            t.v[0] = __float2bfloat16(acc[r][0]);
            t.v[1] = __float2bfloat16(acc[r][1]);
            t.v[2] = __float2bfloat16(acc[r][2]);
            t.v[3] = __float2bfloat16(acc[r][3]);
            *(b4*)&Cb[(size_t)row * ldc + j0 + tx * 4] = t;
        }
    }
}

// ---------------- attention coefficients ----------------

template <int H, int C>
__global__ void al_kernel(const float* __restrict__ h, const float* __restrict__ asrc,
                          const float* __restrict__ adst, float* __restrict__ als,
                          float* __restrict__ ald, int n) {
    int g = blockIdx.x * 256 + threadIdx.x;
    if (g >= n * H) return;
    int head = g % H;
    const float* hp = h + (size_t)(g / H) * (H * C) + head * C;
    const float* sp = asrc + head * C;
    const float* dp = adst + head * C;
    float s = 0.f, d = 0.f;
#pragma unroll
    for (int j = 0; j < C; j += 4) {
        float4 hv = *(const float4*)&hp[j];
        float4 sv = *(const float4*)&sp[j];
        float4 dv = *(const float4*)&dp[j];
        s += hv.x * sv.x + hv.y * sv.y + hv.z * sv.z + hv.w * sv.w;
        d += hv.x * dv.x + hv.y * dv.y + hv.z * dv.z + hv.w * dv.w;
    }
    als[g] = s;
    ald[g] = d;
}

// ---------------- GAT aggregation, 4 heads (F=128), wave per dst node ----------------

__global__ __launch_bounds__(256) void agg4_kernel(
    const char* __restrict__ hb, const float* __restrict__ als, const float* __restrict__ ald,
    const int* __restrict__ offs, const int* __restrict__ cur, const int* __restrict__ csr,
    const float* __restrict__ bias, float* __restrict__ out, int n, int do_l1) {
    __shared__ int soff[4][64];
    __shared__ float sp[4][64][4];
    int w = threadIdx.x >> 6;
    int v = blockIdx.x * 4 + w;
    if (v >= n) return;
    int lane = threadIdx.x & 63;
    int hd = lane >> 4;
    int lane4 = lane << 2;

    float4 av = *(const float4*)&ald[v * 4];
    float4 svv = *(const float4*)&als[v * 4];
    int begin = offs[v], end = cur[v];

    float ps0 = __expf(lrelu(svv.x + av.x, 0.2f));
    float ps1 = __expf(lrelu(svv.y + av.y, 0.2f));
    float ps2 = __expf(lrelu(svv.z + av.z, 0.2f));
    float ps3 = __expf(lrelu(svv.w + av.w, 0.2f));
    float psel = hd == 0 ? ps0 : hd == 1 ? ps1 : hd == 2 ? ps2 : ps3;
    unsigned uv = *(const unsigned*)(hb + (size_t)v * 256 + lane4);
    float acc0 = psel * __uint_as_float(uv << 16);
    float acc1 = psel * __uint_as_float(uv & 0xFFFF0000u);
    float s0 = 0.f, s1 = 0.f, s2 = 0.f, s3 = 0.f;

    for (int base = begin; base < end; base += 64) {
        int idx = base + lane;
        int cnt = min(64, end - base);
        if (idx < end) {
            int s = csr[idx];
            float4 q = *(const float4*)&als[s * 4];
            float p0 = __expf(lrelu(q.x + av.x, 0.2f));
            float p1 = __expf(lrelu(q.y + av.y, 0.2f));
            float p2 = __expf(lrelu(q.z + av.z, 0.2f));
            float p3 = __expf(lrelu(q.w + av.w, 0.2f));
            soff[w][lane] = s << 8;  // byte offset into bf16 rows (128*2B)
            sp[w][lane][0] = p0;
            sp[w][lane][1] = p1;
            sp[w][lane][2] = p2;
            sp[w][lane][3] = p3;
            s0 += p0; s1 += p1; s2 += p2; s3 += p3;
        }
        asm volatile("s_waitcnt lgkmcnt(0)" ::: "memory");
        int t = 0;
        for (; t + 8 <= cnt; t += 8) {
            int o0 = soff[w][t + 0], o1 = soff[w][t + 1];
            int o2 = soff[w][t + 2], o3 = soff[w][t + 3];
            int o4 = soff[w][t + 4], o5 = soff[w][t + 5];
            int o6 = soff[w][t + 6], o7 = soff[w][t + 7];
            float p0 = sp[w][t + 0][hd], p1 = sp[w][t + 1][hd];
            float p2 = sp[w][t + 2][hd], p3 = sp[w][t + 3][hd];
            float p4 = sp[w][t + 4][hd], p5 = sp[w][t + 5][hd];
            float p6 = sp[w][t + 6][hd], p7 = sp[w][t + 7][hd];
            unsigned u0 = *(const unsigned*)(hb + o0 + lane4);
            unsigned u1 = *(const unsigned*)(hb + o1 + lane4);
            unsigned u2 = *(const unsigned*)(hb + o2 + lane4);
            unsigned u3 = *(const unsigned*)(hb + o3 + lane4);
            unsigned u4 = *(const unsigned*)(hb + o4 + lane4);
            unsigned u5 = *(const unsigned*)(hb + o5 + lane4);
            unsigned u6 = *(const unsigned*)(hb + o6 + lane4);
            unsigned u7 = *(const unsigned*)(hb + o7 + lane4);
            acc0 += p0 * __uint_as_float(u0 << 16);
            acc1 += p0 * __uint_as_float(u0 & 0xFFFF0000u);
            acc0 += p1 * __uint_as_float(u1 << 16);
            acc1 += p1 * __uint_as_float(u1 & 0xFFFF0000u);
            acc0 += p2 * __uint_as_float(u2 << 16);
            acc1 += p2 * __uint_as_float(u2 & 0xFFFF0000u);
            acc0 += p3 * __uint_as_float(u3 << 16);
            acc1 += p3 * __uint_as_float(u3 & 0xFFFF0000u);
            acc0 += p4 * __uint_as_float(u4 << 16);
            acc1 += p4 * __uint_as_float(u4 & 0xFFFF0000u);
            acc0 += p5 * __uint_as_float(u5 << 16);
            acc1 += p5 * __uint_as_float(u5 & 0xFFFF0000u);
            acc0 += p6 * __uint_as_float(u6 << 16);
            acc1 += p6 * __uint_as_float(u6 & 0xFFFF0000u);
            acc0 += p7 * __uint_as_float(u7 << 16);
            acc1 += p7 * __uint_as_float(u7 & 0xFFFF0000u);
        }
        for (; t < cnt; ++t) {
            int oa = soff[w][t];
            float pa = sp[w][t][hd];
            unsigned ua = *(const unsigned*)(hb + oa + lane4);
            acc0 += pa * __uint_as_float(ua << 16);
            acc1 += pa * __uint_as_float(ua & 0xFFFF0000u);
        }
    }
#pragma unroll
    for (int o = 32; o > 0; o >>= 1) {
        s0 += __shfl_xor(s0, o);
        s1 += __shfl_xor(s1, o);
        s2 += __shfl_xor(s2, o);
        s3 += __shfl_xor(s3, o);
    }
    s0 += ps0; s1 += ps1; s2 += ps2; s3 += ps3;
    float ssel = hd == 0 ? s0 : hd == 1 ? s1 : hd == 2 ? s2 : s3;
    float inv = 1.f / (ssel + 1e-16f);
    float2 bv = *(const float2*)&bias[2 * lane];
    float o0 = lrelu(acc0 * inv + bv.x, 0.01f);
    float o1 = lrelu(acc1 * inv + bv.y, 0.01f);
    if (do_l1) {
        float t = fabsf(o0) + fabsf(o1);
#pragma unroll
        for (int o = 32; o > 0; o >>= 1) t += __shfl_xor(t, o);
        float li = 1.f / fmaxf(t, 1e-12f);
        o0 *= li;
        o1 *= li;
    }
    *(float2*)&out[(size_t)v * 128 + 2 * lane] = make_float2(o0, o1);
}

// ---------------- GAT aggregation, 1 head x 64 (layer 2) + l1norm + relu -> d_out ---------

__global__ __launch_bounds__(256) void agg1_kernel(
    const char* __restrict__ hb, const float* __restrict__ als, const float* __restrict__ ald,
    const int* __restrict__ offs, const int* __restrict__ cur, const int* __restrict__ csr,
    const float* __restrict__ bias, float* __restrict__ out, int n) {
    __shared__ int soff[4][64];
    __shared__ float sp[4][64];
    int w = threadIdx.x >> 6;
    int v = blockIdx.x * 4 + w;
    if (v >= n) return;
    int lane = threadIdx.x & 63;
    int lane2 = lane << 1;
    float aldv = ald[v];
    float alsv = als[v];
    int begin = offs[v], end = cur[v];

    float pself = __expf(lrelu(alsv + aldv, 0.2f));
    unsigned short usv = *(const unsigned short*)(hb + (size_t)v * 128 + lane2);
    float acc = pself * __uint_as_float(((unsigned)usv) << 16);
    float ssum = 0.f;

    for (int base = begin; base < end; base += 64) {
        int idx = base + lane;
        int cnt = min(64, end - base);
        if (idx < end) {
            int s = csr[idx];
            float p = __expf(lrelu(als[s] + aldv, 0.2f));
            soff[w][lane] = s << 7;  // byte offset into bf16 rows (64*2B)
            sp[w][lane] = p;
            ssum += p;
        }
        asm volatile("s_waitcnt lgkmcnt(0)" ::: "memory");
        int t = 0;
        for (; t + 8 <= cnt; t += 8) {
            int o0 = soff[w][t + 0], o1 = soff[w][t + 1];
            int o2 = soff[w][t + 2], o3 = soff[w][t + 3];
            int o4 = soff[w][t + 4], o5 = soff[w][t + 5];
            int o6 = soff[w][t + 6], o7 = soff[w][t + 7];
            float p0 = sp[w][t + 0], p1 = sp[w][t + 1];
            float p2 = sp[w][t + 2], p3 = sp[w][t + 3];
            float p4 = sp[w][t + 4], p5 = sp[w][t + 5];
            float p6 = sp[w][t + 6], p7 = sp[w][t + 7];
            unsigned short u0 = *(const unsigned short*)(hb + o0 + lane2);
            unsigned short u1 = *(const unsigned short*)(hb + o1 + lane2);
            unsigned short u2 = *(const unsigned short*)(hb + o2 + lane2);
            unsigned short u3 = *(const unsigned short*)(hb + o3 + lane2);
            unsigned short u4 = *(const unsigned short*)(hb + o4 + lane2);
            unsigned short u5 = *(const unsigned short*)(hb + o5 + lane2);
            unsigned short u6 = *(const unsigned short*)(hb + o6 + lane2);
            unsigned short u7 = *(const unsigned short*)(hb + o7 + lane2);
            acc += p0 * __uint_as_float(((unsigned)u0) << 16);
            acc += p1 * __uint_as_float(((unsigned)u1) << 16);
            acc += p2 * __uint_as_float(((unsigned)u2) << 16);
            acc += p3 * __uint_as_float(((unsigned)u3) << 16);
            acc += p4 * __uint_as_float(((unsigned)u4) << 16);
            acc += p5 * __uint_as_float(((unsigned)u5) << 16);
            acc += p6 * __uint_as_float(((unsigned)u6) << 16);
            acc += p7 * __uint_as_float(((unsigned)u7) << 16);
        }
        for (; t < cnt; ++t) {
            int oa = soff[w][t];
            float pa = sp[w][t];
            unsigned short ua = *(const unsigned short*)(hb + oa + lane2);
            acc += pa * __uint_as_float(((unsigned)ua) << 16);
        }
    }
#pragma unroll
    for (int o = 32; o > 0; o >>= 1) ssum += __shfl_xor(ssum, o);
    ssum += pself;
    float o = acc / (ssum + 1e-16f) + bias[lane];
    float t = fabsf(o);
#pragma unroll
    for (int off = 32; off > 0; off >>= 1) t += __shfl_xor(t, off);
    o = o / fmaxf(t, 1e-12f);
    out[(size_t)v * 64 + lane] = fmaxf(o, 0.f);
}

// ---------------- launch ----------------

extern "C" void kernel_launch(void* const* d_in, const int* in_sizes, int n_in,
                              void* d_out, int out_size, void* d_ws, size_t ws_size,
                              hipStream_t stream) {
    const float* x = (const float*)d_in[0];
    const int* ei = (const int*)d_in[1];
    const float* W0 = (const float*)d_in[2];
    const float* b0 = (const float*)d_in[3];
    const float* as0 = (const float*)d_in[4];
    const float* ad0 = (const float*)d_in[5];
    const float* W1 = (const float*)d_in[6];
    const float* b1 = (const float*)d_in[7];
    const float* as1 = (const float*)d_in[8];
    const float* ad1 = (const float*)d_in[9];
    const float* W2 = (const float*)d_in[10];
    const float* b2 = (const float*)d_in[11];
    const float* as2 = (const float*)d_in[12];
    const float* ad2 = (const float*)d_in[13];
    float* outp = (float*)d_out;

    char* ws = (char*)d_ws;
    size_t off = 0;
    auto alloc = [&](size_t bytes) -> void* {
        void* p = ws + off;
        off = (off + bytes + 255) & ~(size_t)255;
        return p;
    };
    int* offs = (int*)alloc((NN + 1) * 4);
    int* bcnt = (int*)alloc(NB * 4);
    int* bbase = (int*)alloc((NB + 1) * 4);
    int* bcursor = (int*)alloc(NB * 4);
    int2* part = (int2*)alloc((size_t)NE * 8);
    int* csr = (int*)alloc((size_t)NE * 4);
    float* hbuf = (float*)alloc((size_t)NN * 128 * 4);
    float* nodeA = (float*)alloc((size_t)NN * 128 * 4);
    __hip_bfloat16* h16 = (__hip_bfloat16*)alloc((size_t)NN * 128 * 2);
    float* als = (float*)alloc(NN * 4 * 4);
    float* ald = (float*)alloc(NN * 4 * 4);

    const int* srcs = ei;
    const int* dsts = ei + NE;

    // CSR build: bucket histogram -> scan -> partition -> per-bucket fill (also emits offs)
    hipMemsetAsync(bcnt, 0, NB * 4, stream);
    bucket_hist<<<NB, 256, 0, stream>>>(dsts, bcnt);
    bucket_scan<<<1, 512, 0, stream>>>(bcnt, bbase, bcursor);
    partition_kernel<<<(NE + CHUNK - 1) / CHUNK, 256, 0, stream>>>(srcs, dsts, bcursor, part);
    bucket_fill<<<NB, 256, 0, stream>>>(part, bbase, offs, csr);

    dim3 ggrid((NN + 63) / 64, 2);
    dim3 ggrid2((NN + 63) / 64, 1);
    int algrid = (NN * 4 + 255) / 256;
    int aggrid = (NN + 3) / 4;

    // layer 0
    gemm_tile<<<ggrid, 256, 0, stream>>>(x, W0, hbuf, h16, NN, 128, 128);
    al_kernel<4, 32><<<algrid, 256, 0, stream>>>(hbuf, as0, ad0, als, ald, NN);
    agg4_kernel<<<aggrid, 256, 0, stream>>>((const char*)h16, als, ald, offs, offs + 1, csr, b0,
                                            nodeA, NN, 1);
    // layer 1
    gemm_tile<<<ggrid, 256, 0, stream>>>(nodeA, W1, hbuf, h16, NN, 128, 128);
    al_kernel<4, 32><<<algrid, 256, 0, stream>>>(hbuf, as1, ad1, als, ald, NN);
    agg4_kernel<<<aggrid, 256, 0, stream>>>((const char*)h16, als, ald, offs, offs + 1, csr, b1,
                                            nodeA, NN, 0);
    // layer 2
    gemm_tile<<<ggrid2, 256, 0, stream>>>(nodeA, W2, hbuf, h16, NN, 64, 64);
    al_kernel<1, 64><<<(NN + 255) / 256, 256, 0, stream>>>(hbuf, as2, ad2, als, ald, NN);
    agg1_kernel<<<aggrid, 256, 0, stream>>>((const char*)h16, als, ald, offs, offs + 1, csr, b2,
                                            outp, NN);
}

// Round 5
// 381.754 us; speedup vs baseline: 2.1754x; 1.3074x over previous
//
#include <hip/hip_runtime.h>
#include <hip/hip_bf16.h>

#define NN 100000
#define NE 1600000
#define NB 391      // buckets of 256 nodes: (100000 + 255) >> 8
#define CHUNK 4096  // edges per partition block

typedef short bf8v __attribute__((ext_vector_type(8)));   // 8 bf16 (4 VGPRs)
typedef float f32x4 __attribute__((ext_vector_type(4)));  // MFMA acc

static __device__ __forceinline__ float lrelu(float x, float s) {
    return x > 0.f ? x : s * x;
}

static __device__ __forceinline__ unsigned short f2b(float f) {
    __hip_bfloat16 b = __float2bfloat16(f);
    return *reinterpret_cast<unsigned short*>(&b);
}

struct alignas(4) bh2 {
    __hip_bfloat16 x, y;
};

// ---------------- CSR build: two-level counting sort ----------------

__global__ __launch_bounds__(256) void bucket_hist(const int* __restrict__ dsts,
                                                   int* __restrict__ bcnt) {
    __shared__ int hist[NB];
    for (int t = threadIdx.x; t < NB; t += 256) hist[t] = 0;
    __syncthreads();
    int stride = gridDim.x * 256;
    for (int e = blockIdx.x * 256 + threadIdx.x; e < NE; e += stride)
        atomicAdd(&hist[dsts[e] >> 8], 1);
    __syncthreads();
    for (int t = threadIdx.x; t < NB; t += 256) {
        int c = hist[t];
        if (c) atomicAdd(&bcnt[t], c);
    }
}

__global__ __launch_bounds__(512) void bucket_scan(const int* __restrict__ bcnt,
                                                   int* __restrict__ bbase,
                                                   int* __restrict__ bcursor) {
    __shared__ int sd[512];
    int t = threadIdx.x;
    int v = (t < NB) ? bcnt[t] : 0;
    sd[t] = v;
    __syncthreads();
    for (int off = 1; off < 512; off <<= 1) {
        int x = (t >= off) ? sd[t - off] : 0;
        __syncthreads();
        sd[t] += x;
        __syncthreads();
    }
    int excl = sd[t] - v;
    if (t < NB) {
        bbase[t] = excl;
        bcursor[t] = excl;
    }
    if (t == NB - 1) bbase[NB] = excl + v;
}

__global__ __launch_bounds__(256) void partition_kernel(const int* __restrict__ srcs,
                                                        const int* __restrict__ dsts,
                                                        int* bcursor,
                                                        int2* __restrict__ part) {
    __shared__ int hist[NB];
    __shared__ int lbase[NB];
    for (int t = threadIdx.x; t < NB; t += 256) hist[t] = 0;
    __syncthreads();
    int e0 = blockIdx.x * CHUNK;
#pragma unroll
    for (int k = 0; k < CHUNK / 256; k++) {
        int e = e0 + k * 256 + threadIdx.x;
        if (e < NE) atomicAdd(&hist[dsts[e] >> 8], 1);
    }
    __syncthreads();
    for (int t = threadIdx.x; t < NB; t += 256) {
        int c = hist[t];
        if (c) lbase[t] = atomicAdd(&bcursor[t], c);
        hist[t] = 0;  // reuse as local cursor
    }
    __syncthreads();
#pragma unroll
    for (int k = 0; k < CHUNK / 256; k++) {
        int e = e0 + k * 256 + threadIdx.x;
        if (e < NE) {
            int s = srcs[e], d = dsts[e];
            int b = d >> 8;
            int r = atomicAdd(&hist[b], 1);
            part[lbase[b] + r] = make_int2(s, d);
        }
    }
}

__global__ __launch_bounds__(256) void bucket_fill(const int2* __restrict__ part,
                                                   const int* __restrict__ bbase,
                                                   int* __restrict__ offs,
                                                   int* __restrict__ csr) {
    __shared__ int lcur[256];
    __shared__ int sd[256];
    int b = blockIdx.x;
    int t = threadIdx.x;
    int ebeg = bbase[b], eend = bbase[b + 1];
    int node0 = b << 8;
    int nNodes = min(256, NN - node0);
    lcur[t] = 0;
    __syncthreads();
    for (int e = ebeg + t; e < eend; e += 256) {
        int2 p = part[e];
        atomicAdd(&lcur[p.y - node0], 1);
    }
    __syncthreads();
    int cnt = lcur[t];
    sd[t] = cnt;
    __syncthreads();
    for (int off = 1; off < 256; off <<= 1) {
        int x = (t >= off) ? sd[t - off] : 0;
        __syncthreads();
        sd[t] += x;
        __syncthreads();
    }
    int start = ebeg + sd[t] - cnt;
    if (t < nNodes) offs[node0 + t] = start;
    if (b == NB - 1 && t == 0) offs[NN] = NE;
    lcur[t] = start;
    __syncthreads();
    for (int e = ebeg + t; e < eend; e += 256) {
        int2 p = part[e];
        int pos = atomicAdd(&lcur[p.y - node0], 1);
        csr[pos] = p.x;
    }
}

// ---------------- fused MFMA GEMM + attention coefficients ----------------
// h = A[n,128] @ W[128,NOUT] (bf16 MFMA, f32 accum). Writes h as bf16 only.
// als/ald computed from f32 accumulators in the epilogue (al_kernel fused away).

template <int NOUT, int HEADS, bool AF32>
__global__ __launch_bounds__(256) void gemm_fused(
    const float* __restrict__ A32, const unsigned short* __restrict__ A16,
    const float* __restrict__ W, const float* __restrict__ asrc,
    const float* __restrict__ adst, unsigned short* __restrict__ h16out,
    float* __restrict__ als, float* __restrict__ ald, int n) {
    constexpr int NF = NOUT / 16;
    constexpr int PITCH = 136;  // pad 128 -> 136 elems: kills LDS bank conflicts
    __shared__ unsigned short Wl[NOUT * PITCH];

    const int tid = threadIdx.x;
    // stage W (f32 [128][NOUT]) transposed into LDS as bf16 Wl[c][k]
    for (int i = tid; i < (128 * NOUT) / 4; i += 256) {
        int idx = i * 4;
        int k = idx / NOUT;
        int c = idx - k * NOUT;
        float4 wv = *(const float4*)&W[idx];
        Wl[(c + 0) * PITCH + k] = f2b(wv.x);
        Wl[(c + 1) * PITCH + k] = f2b(wv.y);
        Wl[(c + 2) * PITCH + k] = f2b(wv.z);
        Wl[(c + 3) * PITCH + k] = f2b(wv.w);
    }
    __syncthreads();

    const int lane = tid & 63, wave = tid >> 6;
    const int c = lane & 15, hi = lane >> 4;
    const int r0 = blockIdx.x * 64;
    const int arow = min(r0 + wave * 16 + c, n - 1);  // A-frag row = lane&15
    const int kb = hi * 8;

    f32x4 acc[NF];
#pragma unroll
    for (int nf = 0; nf < NF; ++nf) acc[nf] = 0;

#pragma unroll
    for (int kc = 0; kc < 4; ++kc) {
        bf8v a;
        if constexpr (AF32) {
            const float* ap = A32 + (size_t)arow * 128 + kc * 32 + kb;
            float4 f0 = *(const float4*)ap;
            float4 f1 = *(const float4*)(ap + 4);
            union {
                bf8v v;
                unsigned short u[8];
            } ua;
            ua.u[0] = f2b(f0.x);
            ua.u[1] = f2b(f0.y);
            ua.u[2] = f2b(f0.z);
            ua.u[3] = f2b(f0.w);
            ua.u[4] = f2b(f1.x);
            ua.u[5] = f2b(f1.y);
            ua.u[6] = f2b(f1.z);
            ua.u[7] = f2b(f1.w);
            a = ua.v;
        } else {
            a = *(const bf8v*)(A16 + (size_t)arow * 128 + kc * 32 + kb);
        }
#pragma unroll
        for (int nf = 0; nf < NF; ++nf) {
            bf8v b = *(const bf8v*)&Wl[(nf * 16 + c) * PITCH + kc * 32 + kb];
            acc[nf] = __builtin_amdgcn_mfma_f32_16x16x32_bf16(a, b, acc[nf], 0, 0, 0);
        }
    }

    // ---- epilogue 1: als/ald from f32 accumulators ----
    // C/D layout: col = nf*16 + (lane&15), row = r0 + wave*16 + hi*4 + reg
    float aS[NF], aD[NF];
#pragma unroll
    for (int nf = 0; nf < NF; ++nf) {
        aS[nf] = asrc[nf * 16 + c];
        aD[nf] = adst[nf * 16 + c];
    }
    float sRes[HEADS][4], dRes[HEADS][4];
#pragma unroll
    for (int hh = 0; hh < HEADS; ++hh) {
#pragma unroll
        for (int reg = 0; reg < 4; ++reg) {
            float s = 0.f, d = 0.f;
#pragma unroll
            for (int nf = hh * (NF / HEADS); nf < (hh + 1) * (NF / HEADS); ++nf) {
                s += acc[nf][reg] * aS[nf];
                d += acc[nf][reg] * aD[nf];
            }
#pragma unroll
            for (int o = 1; o < 16; o <<= 1) {  // reduce over the 16 col-lanes
                s += __shfl_xor(s, o);
                d += __shfl_xor(d, o);
            }
            sRes[hh][reg] = s;
            dRes[hh][reg] = d;
        }
    }
    if (c == 0) {
#pragma unroll
        for (int reg = 0; reg < 4; ++reg) {
            int ro = r0 + wave * 16 + hi * 4 + reg;
            if (ro < n) {
                if constexpr (HEADS == 4) {
                    *(float4*)&als[ro * 4] =
                        make_float4(sRes[0][reg], sRes[1][reg], sRes[2][reg], sRes[3][reg]);
                    *(float4*)&ald[ro * 4] =
                        make_float4(dRes[0][reg], dRes[1][reg], dRes[2][reg], dRes[3][reg]);
                } else {
                    als[ro] = sRes[0][reg];
                    ald[ro] = dRes[0][reg];
                }
            }
        }
    }

    // ---- epilogue 2: h -> bf16 via LDS transpose, coalesced store ----
    __syncthreads();  // all waves done reading Wl
#pragma unroll
    for (int nf = 0; nf < NF; ++nf) {
#pragma unroll
        for (int reg = 0; reg < 4; ++reg) {
            int rl = wave * 16 + hi * 4 + reg;
            Wl[rl * PITCH + nf * 16 + c] = f2b(acc[nf][reg]);
        }
    }
    __syncthreads();
    constexpr int SEGS = NOUT / 8;
    for (int i = tid; i < 64 * SEGS; i += 256) {
        int rl = i / SEGS, sg = i - rl * SEGS;
        int ro = r0 + rl;
        if (ro < n)
            *(uint4*)&h16out[(size_t)ro * NOUT + sg * 8] =
                *(const uint4*)&Wl[rl * PITCH + sg * 8];
    }
}

// ---------------- GAT aggregation, 4 heads (F=128), wave per dst node ----------------

__global__ __launch_bounds__(256) void agg4_kernel(
    const char* __restrict__ hb, const float* __restrict__ als, const float* __restrict__ ald,
    const int* __restrict__ offs, const int* __restrict__ cur, const int* __restrict__ csr,
    const float* __restrict__ bias, __hip_bfloat16* __restrict__ out, int n, int do_l1) {
    __shared__ int soff[4][64];
    __shared__ float sp[4][64][4];
    int w = threadIdx.x >> 6;
    int v = blockIdx.x * 4 + w;
    if (v >= n) return;
    int lane = threadIdx.x & 63;
    int hd = lane >> 4;
    int lane4 = lane << 2;

    float4 av = *(const float4*)&ald[v * 4];
    float4 svv = *(const float4*)&als[v * 4];
    int begin = offs[v], end = cur[v];

    float ps0 = __expf(lrelu(svv.x + av.x, 0.2f));
    float ps1 = __expf(lrelu(svv.y + av.y, 0.2f));
    float ps2 = __expf(lrelu(svv.z + av.z, 0.2f));
    float ps3 = __expf(lrelu(svv.w + av.w, 0.2f));
    float psel = hd == 0 ? ps0 : hd == 1 ? ps1 : hd == 2 ? ps2 : ps3;
    unsigned uv = *(const unsigned*)(hb + (size_t)v * 256 + lane4);
    float acc0 = psel * __uint_as_float(uv << 16);
    float acc1 = psel * __uint_as_float(uv & 0xFFFF0000u);
    float s0 = 0.f, s1 = 0.f, s2 = 0.f, s3 = 0.f;

    for (int base = begin; base < end; base += 64) {
        int idx = base + lane;
        int cnt = min(64, end - base);
        if (idx < end) {
            int s = csr[idx];
            float4 q = *(const float4*)&als[s * 4];
            float p0 = __expf(lrelu(q.x + av.x, 0.2f));
            float p1 = __expf(lrelu(q.y + av.y, 0.2f));
            float p2 = __expf(lrelu(q.z + av.z, 0.2f));
            float p3 = __expf(lrelu(q.w + av.w, 0.2f));
            soff[w][lane] = s << 8;  // byte offset into bf16 rows (128*2B)
            sp[w][lane][0] = p0;
            sp[w][lane][1] = p1;
            sp[w][lane][2] = p2;
            sp[w][lane][3] = p3;
            s0 += p0; s1 += p1; s2 += p2; s3 += p3;
        }
        asm volatile("s_waitcnt lgkmcnt(0)" ::: "memory");
        int t = 0;
        for (; t + 8 <= cnt; t += 8) {
            int o0 = soff[w][t + 0], o1 = soff[w][t + 1];
            int o2 = soff[w][t + 2], o3 = soff[w][t + 3];
            int o4 = soff[w][t + 4], o5 = soff[w][t + 5];
            int o6 = soff[w][t + 6], o7 = soff[w][t + 7];
            float p0 = sp[w][t + 0][hd], p1 = sp[w][t + 1][hd];
            float p2 = sp[w][t + 2][hd], p3 = sp[w][t + 3][hd];
            float p4 = sp[w][t + 4][hd], p5 = sp[w][t + 5][hd];
            float p6 = sp[w][t + 6][hd], p7 = sp[w][t + 7][hd];
            unsigned u0 = *(const unsigned*)(hb + o0 + lane4);
            unsigned u1 = *(const unsigned*)(hb + o1 + lane4);
            unsigned u2 = *(const unsigned*)(hb + o2 + lane4);
            unsigned u3 = *(const unsigned*)(hb + o3 + lane4);
            unsigned u4 = *(const unsigned*)(hb + o4 + lane4);
            unsigned u5 = *(const unsigned*)(hb + o5 + lane4);
            unsigned u6 = *(const unsigned*)(hb + o6 + lane4);
            unsigned u7 = *(const unsigned*)(hb + o7 + lane4);
            acc0 += p0 * __uint_as_float(u0 << 16);
            acc1 += p0 * __uint_as_float(u0 & 0xFFFF0000u);
            acc0 += p1 * __uint_as_float(u1 << 16);
            acc1 += p1 * __uint_as_float(u1 & 0xFFFF0000u);
            acc0 += p2 * __uint_as_float(u2 << 16);
            acc1 += p2 * __uint_as_float(u2 & 0xFFFF0000u);
            acc0 += p3 * __uint_as_float(u3 << 16);
            acc1 += p3 * __uint_as_float(u3 & 0xFFFF0000u);
            acc0 += p4 * __uint_as_float(u4 << 16);
            acc1 += p4 * __uint_as_float(u4 & 0xFFFF0000u);
            acc0 += p5 * __uint_as_float(u5 << 16);
            acc1 += p5 * __uint_as_float(u5 & 0xFFFF0000u);
            acc0 += p6 * __uint_as_float(u6 << 16);
            acc1 += p6 * __uint_as_float(u6 & 0xFFFF0000u);
            acc0 += p7 * __uint_as_float(u7 << 16);
            acc1 += p7 * __uint_as_float(u7 & 0xFFFF0000u);
        }
        for (; t < cnt; ++t) {
            int oa = soff[w][t];
            float pa = sp[w][t][hd];
            unsigned ua = *(const unsigned*)(hb + oa + lane4);
            acc0 += pa * __uint_as_float(ua << 16);
            acc1 += pa * __uint_as_float(ua & 0xFFFF0000u);
        }
    }
#pragma unroll
    for (int o = 32; o > 0; o >>= 1) {
        s0 += __shfl_xor(s0, o);
        s1 += __shfl_xor(s1, o);
        s2 += __shfl_xor(s2, o);
        s3 += __shfl_xor(s3, o);
    }
    s0 += ps0; s1 += ps1; s2 += ps2; s3 += ps3;
    float ssel = hd == 0 ? s0 : hd == 1 ? s1 : hd == 2 ? s2 : s3;
    float inv = 1.f / (ssel + 1e-16f);
    float2 bv = *(const float2*)&bias[2 * lane];
    float o0 = lrelu(acc0 * inv + bv.x, 0.01f);
    float o1 = lrelu(acc1 * inv + bv.y, 0.01f);
    if (do_l1) {
        float t = fabsf(o0) + fabsf(o1);
#pragma unroll
        for (int o = 32; o > 0; o >>= 1) t += __shfl_xor(t, o);
        float li = 1.f / fmaxf(t, 1e-12f);
        o0 *= li;
        o1 *= li;
    }
    bh2 pk;
    pk.x = __float2bfloat16(o0);
    pk.y = __float2bfloat16(o1);
    *(bh2*)&out[(size_t)v * 128 + 2 * lane] = pk;
}

// ---------------- GAT aggregation, 1 head x 64 (layer 2) + l1norm + relu -> d_out ---------

__global__ __launch_bounds__(256) void agg1_kernel(
    const char* __restrict__ hb, const float* __restrict__ als, const float* __restrict__ ald,
    const int* __restrict__ offs, const int* __restrict__ cur, const int* __restrict__ csr,
    const float* __restrict__ bias, float* __restrict__ out, int n) {
    __shared__ int soff[4][64];
    __shared__ float sp[4][64];
    int w = threadIdx.x >> 6;
    int v = blockIdx.x * 4 + w;
    if (v >= n) return;
    int lane = threadIdx.x & 63;
    int lane2 = lane << 1;
    float aldv = ald[v];
    float alsv = als[v];
    int begin = offs[v], end = cur[v];

    float pself = __expf(lrelu(alsv + aldv, 0.2f));
    unsigned short usv = *(const unsigned short*)(hb + (size_t)v * 128 + lane2);
    float acc = pself * __uint_as_float(((unsigned)usv) << 16);
    float ssum = 0.f;

    for (int base = begin; base < end; base += 64) {
        int idx = base + lane;
        int cnt = min(64, end - base);
        if (idx < end) {
            int s = csr[idx];
            float p = __expf(lrelu(als[s] + aldv, 0.2f));
            soff[w][lane] = s << 7;  // byte offset into bf16 rows (64*2B)
            sp[w][lane] = p;
            ssum += p;
        }
        asm volatile("s_waitcnt lgkmcnt(0)" ::: "memory");
        int t = 0;
        for (; t + 8 <= cnt; t += 8) {
            int o0 = soff[w][t + 0], o1 = soff[w][t + 1];
            int o2 = soff[w][t + 2], o3 = soff[w][t + 3];
            int o4 = soff[w][t + 4], o5 = soff[w][t + 5];
            int o6 = soff[w][t + 6], o7 = soff[w][t + 7];
            float p0 = sp[w][t + 0], p1 = sp[w][t + 1];
            float p2 = sp[w][t + 2], p3 = sp[w][t + 3];
            float p4 = sp[w][t + 4], p5 = sp[w][t + 5];
            float p6 = sp[w][t + 6], p7 = sp[w][t + 7];
            unsigned short u0 = *(const unsigned short*)(hb + o0 + lane2);
            unsigned short u1 = *(const unsigned short*)(hb + o1 + lane2);
            unsigned short u2 = *(const unsigned short*)(hb + o2 + lane2);
            unsigned short u3 = *(const unsigned short*)(hb + o3 + lane2);
            unsigned short u4 = *(const unsigned short*)(hb + o4 + lane2);
            unsigned short u5 = *(const unsigned short*)(hb + o5 + lane2);
            unsigned short u6 = *(const unsigned short*)(hb + o6 + lane2);
            unsigned short u7 = *(const unsigned short*)(hb + o7 + lane2);
            acc += p0 * __uint_as_float(((unsigned)u0) << 16);
            acc += p1 * __uint_as_float(((unsigned)u1) << 16);
            acc += p2 * __uint_as_float(((unsigned)u2) << 16);
            acc += p3 * __uint_as_float(((unsigned)u3) << 16);
            acc += p4 * __uint_as_float(((unsigned)u4) << 16);
            acc += p5 * __uint_as_float(((unsigned)u5) << 16);
            acc += p6 * __uint_as_float(((unsigned)u6) << 16);
            acc += p7 * __uint_as_float(((unsigned)u7) << 16);
        }
        for (; t < cnt; ++t) {
            int oa = soff[w][t];
            float pa = sp[w][t];
            unsigned short ua = *(const unsigned short*)(hb + oa + lane2);
            acc += pa * __uint_as_float(((unsigned)ua) << 16);
        }
    }
#pragma unroll
    for (int o = 32; o > 0; o >>= 1) ssum += __shfl_xor(ssum, o);
    ssum += pself;
    float o = acc / (ssum + 1e-16f) + bias[lane];
    float t = fabsf(o);
#pragma unroll
    for (int off = 32; off > 0; off >>= 1) t += __shfl_xor(t, off);
    o = o / fmaxf(t, 1e-12f);
    out[(size_t)v * 64 + lane] = fmaxf(o, 0.f);
}

// ---------------- launch ----------------

extern "C" void kernel_launch(void* const* d_in, const int* in_sizes, int n_in,
                              void* d_out, int out_size, void* d_ws, size_t ws_size,
                              hipStream_t stream) {
    const float* x = (const float*)d_in[0];
    const int* ei = (const int*)d_in[1];
    const float* W0 = (const float*)d_in[2];
    const float* b0 = (const float*)d_in[3];
    const float* as0 = (const float*)d_in[4];
    const float* ad0 = (const float*)d_in[5];
    const float* W1 = (const float*)d_in[6];
    const float* b1 = (const float*)d_in[7];
    const float* as1 = (const float*)d_in[8];
    const float* ad1 = (const float*)d_in[9];
    const float* W2 = (const float*)d_in[10];
    const float* b2 = (const float*)d_in[11];
    const float* as2 = (const float*)d_in[12];
    const float* ad2 = (const float*)d_in[13];
    float* outp = (float*)d_out;

    char* ws = (char*)d_ws;
    size_t off = 0;
    auto alloc = [&](size_t bytes) -> void* {
        void* p = ws + off;
        off = (off + bytes + 255) & ~(size_t)255;
        return p;
    };
    int* offs = (int*)alloc((NN + 1) * 4);
    int* bcnt = (int*)alloc(NB * 4);
    int* bbase = (int*)alloc((NB + 1) * 4);
    int* bcursor = (int*)alloc(NB * 4);
    int2* part = (int2*)alloc((size_t)NE * 8);
    int* csr = (int*)alloc((size_t)NE * 4);
    unsigned short* h16 = (unsigned short*)alloc((size_t)NN * 128 * 2);
    unsigned short* a16 = (unsigned short*)alloc((size_t)NN * 128 * 2);
    float* als = (float*)alloc(NN * 4 * 4);
    float* ald = (float*)alloc(NN * 4 * 4);

    const int* srcs = ei;
    const int* dsts = ei + NE;

    // CSR build
    hipMemsetAsync(bcnt, 0, NB * 4, stream);
    bucket_hist<<<NB, 256, 0, stream>>>(dsts, bcnt);
    bucket_scan<<<1, 512, 0, stream>>>(bcnt, bbase, bcursor);
    partition_kernel<<<(NE + CHUNK - 1) / CHUNK, 256, 0, stream>>>(srcs, dsts, bcursor, part);
    bucket_fill<<<NB, 256, 0, stream>>>(part, bbase, offs, csr);

    int ggrid = (NN + 63) / 64;  // 1563
    int aggrid = (NN + 3) / 4;

    // layer 0
    gemm_fused<128, 4, true><<<ggrid, 256, 0, stream>>>(x, nullptr, W0, as0, ad0, h16, als, ald,
                                                        NN);
    agg4_kernel<<<aggrid, 256, 0, stream>>>((const char*)h16, als, ald, offs, offs + 1, csr, b0,
                                            (__hip_bfloat16*)a16, NN, 1);
    // layer 1
    gemm_fused<128, 4, false><<<ggrid, 256, 0, stream>>>(nullptr, a16, W1, as1, ad1, h16, als,
                                                         ald, NN);
    agg4_kernel<<<aggrid, 256, 0, stream>>>((const char*)h16, als, ald, offs, offs + 1, csr, b1,
                                            (__hip_bfloat16*)a16, NN, 0);
    // layer 2
    gemm_fused<64, 1, false><<<ggrid, 256, 0, stream>>>(nullptr, a16, W2, as2, ad2, h16, als,
                                                        ald, NN);
    agg1_kernel<<<aggrid, 256, 0, stream>>>((const char*)h16, als, ald, offs, offs + 1, csr, b2,
                                            outp, NN);
}